// Round 10
// baseline (6001.698 us; speedup 1.0000x reference)
//
#include <hip/hip_runtime.h>
#include <hip/hip_bf16.h>
#include <math.h>

#define B_ 32
#define T_ 512
#define D_ 1024
#define H_ 1024
#define G4 4096
#define BT 16384
#define NWG 64

using bf16x8 = __attribute__((ext_vector_type(8))) short;
using f32x4  = __attribute__((ext_vector_type(4))) float;
typedef unsigned long long u64;
typedef unsigned int u32;

__device__ __forceinline__ float sigm(float x) { return 1.0f / (1.0f + __expf(-x)); }

// ---- workspace layout (bytes) ----
#define OFF_FLG   0ull                          // 64 flags, 64B stride = 4096
#define OFF_WHB   4096ull                       // Wh bf16 [4096][1024] = 8388608
#define OFF_WXB   (OFF_WHB + 8388608ull)        // Wx bf16 = 8388608
#define OFF_INPB  (OFF_WXB + 8388608ull)        // inp bf16 (reused as hseq[T][B][H]) = 33554432
#define OFF_BXH   (OFF_INPB + 33554432ull)      // bx+bh f32 [4096] = 16384
#define OFF_XG    (OFF_BXH + 16384ull)          // xg bf16 [T][NWG][4][32][16] = 134217728
#define WS_NEEDED (OFF_XG + 134217728ull)

// ============ phase 1: convert inputs to bf16, fold biases ============
__global__ __launch_bounds__(256) void convert_all(
    const float* __restrict__ inp, const float* __restrict__ Wx,
    const float* __restrict__ bx, const float* __restrict__ Wh,
    const float* __restrict__ bh,
    __hip_bfloat16* __restrict__ inp_b, __hip_bfloat16* __restrict__ Wx_b,
    __hip_bfloat16* __restrict__ Wh_b, float* __restrict__ bxh)
{
    const int gid = blockIdx.x * 256 + threadIdx.x;   // 0 .. 1048575
    {
        const float4* s = (const float4*)inp + (size_t)gid * 4;
        #pragma unroll
        for (int v = 0; v < 4; ++v) {
            float4 f = s[v];
            size_t base = (size_t)gid * 16 + v * 4;
            inp_b[base + 0] = __float2bfloat16(f.x);
            inp_b[base + 1] = __float2bfloat16(f.y);
            inp_b[base + 2] = __float2bfloat16(f.z);
            inp_b[base + 3] = __float2bfloat16(f.w);
        }
    }
    {
        float4 fx = ((const float4*)Wx)[gid];
        float4 fh = ((const float4*)Wh)[gid];
        size_t base = (size_t)gid * 4;
        Wx_b[base + 0] = __float2bfloat16(fx.x);
        Wx_b[base + 1] = __float2bfloat16(fx.y);
        Wx_b[base + 2] = __float2bfloat16(fx.z);
        Wx_b[base + 3] = __float2bfloat16(fx.w);
        Wh_b[base + 0] = __float2bfloat16(fh.x);
        Wh_b[base + 1] = __float2bfloat16(fh.y);
        Wh_b[base + 2] = __float2bfloat16(fh.z);
        Wh_b[base + 3] = __float2bfloat16(fh.w);
    }
    if (gid < G4) bxh[gid] = bx[gid] + bh[gid];
}

// ============ phase 2: xg = X @ Wx^T + (bx+bh)  (128x128 LDS-staged, T2 swizzle) ============
__global__ __launch_bounds__(256) void xg_gemm(
    const __hip_bfloat16* __restrict__ X,    // [BT][D], row = b*T + t
    const __hip_bfloat16* __restrict__ Wxb,  // [G4][D]
    const float* __restrict__ bxh,           // [G4]
    __hip_bfloat16* __restrict__ xg)         // [T][NWG][4][32][16]
{
    __shared__ __align__(16) char As[16384];
    __shared__ __align__(16) char Bs[16384];

    const int m0 = blockIdx.x * 128;
    const int n0 = blockIdx.y * 128;
    const int tid = threadIdx.x;
    const int lane = tid & 63;
    const int wv = tid >> 6;              // 0..3
    const int vr = wv >> 1, vc = wv & 1;  // 64x64 quadrant
    const int l15 = lane & 15;
    const int kg = (lane >> 4) * 8;

    const int srow_ = wv * 32 + (lane >> 3);
    const int scolb = (lane & 7) * 16;

    f32x4 acc[4][4] = {};

    for (int k0 = 0; k0 < D_; k0 += 64) {
        #pragma unroll
        for (int c = 0; c < 4; ++c) {
            const int row = srow_ + c * 8;
            const int cb  = scolb ^ ((row & 7) << 4);
            const char* ga = (const char*)X   + (size_t)(m0 + row) * 2048 + k0 * 2 + cb;
            const char* gb = (const char*)Wxb + (size_t)(n0 + row) * 2048 + k0 * 2 + cb;
            __builtin_amdgcn_global_load_lds(
                (const __attribute__((address_space(1))) void*)ga,
                (__attribute__((address_space(3))) void*)(As + wv * 4096 + c * 1024),
                16, 0, 0);
            __builtin_amdgcn_global_load_lds(
                (const __attribute__((address_space(1))) void*)gb,
                (__attribute__((address_space(3))) void*)(Bs + wv * 4096 + c * 1024),
                16, 0, 0);
        }
        __syncthreads();

        #pragma unroll
        for (int kk = 0; kk < 64; kk += 32) {
            bf16x8 af[4], bf[4];
            #pragma unroll
            for (int mi = 0; mi < 4; ++mi) {
                const int row = vr * 64 + mi * 16 + l15;
                af[mi] = *(const bf16x8*)(As + row * 128 + (((kk + kg) * 2) ^ ((row & 7) << 4)));
            }
            #pragma unroll
            for (int ni = 0; ni < 4; ++ni) {
                const int col = vc * 64 + ni * 16 + l15;
                bf[ni] = *(const bf16x8*)(Bs + col * 128 + (((kk + kg) * 2) ^ ((col & 7) << 4)));
            }
            #pragma unroll
            for (int mi = 0; mi < 4; ++mi)
                #pragma unroll
                for (int ni = 0; ni < 4; ++ni)
                    acc[mi][ni] = __builtin_amdgcn_mfma_f32_16x16x32_bf16(
                        af[mi], bf[ni], acc[mi][ni], 0, 0, 0);
        }
        __syncthreads();
    }

    #pragma unroll
    for (int ni = 0; ni < 4; ++ni) {
        const int col = n0 + vc * 64 + ni * 16 + l15;
        const int qq = col >> 10, ww = (col >> 4) & 63, jj = col & 15;
        const float bias = bxh[col];
        #pragma unroll
        for (int mi = 0; mi < 4; ++mi) {
            const int r0 = m0 + vr * 64 + mi * 16 + ((lane >> 4) << 2);
            #pragma unroll
            for (int r = 0; r < 4; ++r) {
                const int row = r0 + r;                 // = b*T + t
                const int bb = row >> 9, tt = row & 511;
                xg[(((size_t)tt * NWG + ww) * 4 + qq) * 512 + bb * 16 + jj] =
                    __float2bfloat16(acc[mi][ni][r] + bias);
            }
        }
    }
}

// ============ phase 3: persistent recurrent scan — LDS-free data path ============
// 64 WGs x 512 threads. Wave = (mwave, jg): B-frag row for lane l15 is gate col
// q*1024 + w*16 + jg*4 + j4  (q=l15>>2, j4=l15&3) -> each wave's C tile holds all
// 4 gates for 4 h-cols x 16 batches. Gates combine in-register via shfl_xor(4/8/12).
// A-frags read directly from hseq (global, LLC/L2). One barrier per step.
__global__ __launch_bounds__(512) void lstm_scan(
    const __hip_bfloat16* __restrict__ xg,    // [T][NWG][4][32][16] (bias folded)
    const __hip_bfloat16* __restrict__ Whb,   // [G4][H]
    float* __restrict__ out,                  // [B][T][H] f32
    __hip_bfloat16* __restrict__ hseq,        // [T][B][H]
    unsigned int* __restrict__ flags)         // [NWG] at 64B stride
{
    __shared__ int lds_flag;

    const int w    = blockIdx.x;
    const int tid  = threadIdx.x;
    const int lane = tid & 63;
    const int wave = tid >> 6;
    const int mwave = wave >> 2;       // 0..1
    const int jg    = wave & 3;        // 4-col group
    const int l15   = lane & 15;
    const int hi    = lane >> 4;       // 0..3
    const int kg    = hi * 8;          // k-octet (elements)
    const int q     = l15 >> 2;        // gate index of this lane's B column
    const int j4    = l15 & 3;         // col within group

    if (tid == 0) lds_flag = 0;

    // ---- pin Wh B-fragments: row = gate col q*1024 + w*16 + jg*4 + j4 ----
    bf16x8 bfrag[32];
    {
        const char* wrow = (const char*)(Whb + (size_t)(q * 1024 + w * 16 + jg * 4 + j4) * H_);
        #pragma unroll
        for (int i = 0; i < 32; ++i) {
            u64 lo = __hip_atomic_load((const u64*)(wrow + (i * 32 + kg) * 2),
                                       __ATOMIC_RELAXED, __HIP_MEMORY_SCOPE_AGENT);
            u64 hi_ = __hip_atomic_load((const u64*)(wrow + (i * 32 + kg) * 2 + 8),
                                        __ATOMIC_RELAXED, __HIP_MEMORY_SCOPE_AGENT);
            union { u64 qv[2]; bf16x8 v; } u;
            u.qv[0] = lo; u.qv[1] = hi_;
            bfrag[i] = u.v;
        }
    }

    const int dbr  = mwave * 16 + hi * 4;          // batch base of this lane's C rows
    const int jcol = w * 16 + jg * 4 + j4;         // h column this lane publishes
    const int pbb  = dbr + q;                      // batch this lane publishes (r = q)
    float cst[4] = {0.f, 0.f, 0.f, 0.f};           // c state for (dbr+r, jcol)

    for (int t = 0; t < T_; ++t) {
        // xg prefetch (independent of h; in flight during the wait)
        float xgv[4];
        {
            const size_t sbase = (((size_t)t * NWG + w) * 4 + q) * 512;
            #pragma unroll
            for (int r = 0; r < 4; ++r)
                xgv[r] = __bfloat162float(xg[sbase + (dbr + r) * 16 + (jg * 4 + j4)]);
        }

        f32x4 acc = {};
        if (t > 0) {
            // ---- arrival: wave0 polls 64 flags, relays via LDS; others spin LDS ----
            if (wave == 0) {
                const unsigned int* fp = flags + lane * 16;
                while (__hip_atomic_load(fp, __ATOMIC_RELAXED, __HIP_MEMORY_SCOPE_AGENT)
                       < (unsigned)t)
                    __builtin_amdgcn_s_sleep(1);
                __hip_atomic_store(&lds_flag, t, __ATOMIC_RELAXED,
                                   __HIP_MEMORY_SCOPE_WORKGROUP);
            } else {
                while (__hip_atomic_load(&lds_flag, __ATOMIC_RELAXED,
                                         __HIP_MEMORY_SCOPE_WORKGROUP) < t)
                    __builtin_amdgcn_s_sleep(1);
            }
            asm volatile("" ::: "memory");

            // ---- 32 MFMAs, A-frags straight from global (row = mwave*16 + l15) ----
            const __hip_bfloat16* hrow =
                hseq + ((size_t)(t - 1) * B_ + mwave * 16 + l15) * H_ + kg;
            f32x4 a0 = {}, a1 = {}, a2 = {}, a3 = {};
            #pragma unroll
            for (int i = 0; i < 8; ++i) {
                bf16x8 v0 = *(const bf16x8*)(hrow + (4 * i + 0) * 32);
                bf16x8 v1 = *(const bf16x8*)(hrow + (4 * i + 1) * 32);
                bf16x8 v2 = *(const bf16x8*)(hrow + (4 * i + 2) * 32);
                bf16x8 v3 = *(const bf16x8*)(hrow + (4 * i + 3) * 32);
                a0 = __builtin_amdgcn_mfma_f32_16x16x32_bf16(v0, bfrag[4 * i + 0], a0, 0, 0, 0);
                a1 = __builtin_amdgcn_mfma_f32_16x16x32_bf16(v1, bfrag[4 * i + 1], a1, 0, 0, 0);
                a2 = __builtin_amdgcn_mfma_f32_16x16x32_bf16(v2, bfrag[4 * i + 2], a2, 0, 0, 0);
                a3 = __builtin_amdgcn_mfma_f32_16x16x32_bf16(v3, bfrag[4 * i + 3], a3, 0, 0, 0);
            }
            acc = (a0 + a1) + (a2 + a3);
        }

        // ---- in-wave gate combine + pointwise (4x redundant across q-lanes) ----
        float h4[4];
        #pragma unroll
        for (int r = 0; r < 4; ++r) {
            float v  = acc[r] + xgv[r];
            float xb = __shfl_xor(v, 4, 64);
            float xc = __shfl_xor(v, 8, 64);
            float xd = __shfl_xor(v, 12, 64);
            // gate e lives at shuffle index q^e: 0->v, 1->xb, 2->xc, 3->xd
            float g0 = (q == 0) ? v : (q == 1) ? xb : (q == 2) ? xc : xd;
            float g1 = (q == 1) ? v : (q == 0) ? xb : (q == 3) ? xc : xd;
            float g2 = (q == 2) ? v : (q == 3) ? xb : (q == 0) ? xc : xd;
            float g3 = (q == 3) ? v : (q == 2) ? xb : (q == 1) ? xc : xd;
            float gi = sigm(g0), gf = sigm(g1), gg = sigm(g2), go = sigm(g3);
            cst[r] = cst[r] * gf + gi * gg;
            h4[r] = go * tanhf(cst[r]);
        }

        // ---- publish h (lane r=q cell), shfl-pack 4 cols -> one u64 UC store ----
        float hpub = (q == 0) ? h4[0] : (q == 1) ? h4[1] : (q == 2) ? h4[2] : h4[3];
        {
            __hip_bfloat16 hb = __float2bfloat16(hpub);
            unsigned short hs_;
            __builtin_memcpy(&hs_, &hb, 2);
            u32 hu = hs_;
            u32 x1 = __shfl_xor(hu, 1, 64);
            u32 lo = hu | (x1 << 16);              // valid on even j4
            u32 x2 = __shfl_xor(lo, 2, 64);
            if (j4 == 0) {
                u64 val = (u64)lo | ((u64)x2 << 32);
                u64* dst = (u64*)(hseq + ((size_t)t * B_ + pbb) * H_ + w * 16 + jg * 4);
                __hip_atomic_store(dst, val, __ATOMIC_RELAXED, __HIP_MEMORY_SCOPE_AGENT);
            }
        }
        asm volatile("s_waitcnt vmcnt(0)" ::: "memory");  // h stores acked at coherence point
        __syncthreads();                                   // all waves' stores acked
        if (tid == 0 && t < T_ - 1)
            __hip_atomic_store(flags + w * 16, (unsigned)(t + 1),
                               __ATOMIC_RELAXED, __HIP_MEMORY_SCOPE_AGENT);

        out[((size_t)pbb * T_ + t) * H_ + jcol] = hpub;   // shadow time
    }
}

// ============ fallback (round-1 slow path) if ws too small ============
__global__ __launch_bounds__(256) void lstm_step(
    const float* __restrict__ inp, const float* __restrict__ Wx,
    const float* __restrict__ bx, const float* __restrict__ Wh,
    const float* __restrict__ bh, float* __restrict__ out,
    float* __restrict__ c_state, int t)
{
    const int tid = threadIdx.x;
    const int lane = tid & 63;
    const int khalf = lane & 1;
    const int b = lane >> 1;
    const int j = blockIdx.x * 4 + (tid >> 6);
    const int k0 = khalf * (D_ / 2);
    float a0 = 0.f, a1 = 0.f, a2 = 0.f, a3 = 0.f;
    {
        const float* xrow = inp + ((size_t)b * T_ + t) * D_ + k0;
        const float* w0 = Wx + (size_t)(0 * H_ + j) * D_ + k0;
        const float* w1 = Wx + (size_t)(1 * H_ + j) * D_ + k0;
        const float* w2 = Wx + (size_t)(2 * H_ + j) * D_ + k0;
        const float* w3 = Wx + (size_t)(3 * H_ + j) * D_ + k0;
        for (int kk = 0; kk < D_ / 2; kk += 4) {
            float4 xv = *(const float4*)(xrow + kk);
            float4 v0 = *(const float4*)(w0 + kk), v1 = *(const float4*)(w1 + kk);
            float4 v2 = *(const float4*)(w2 + kk), v3 = *(const float4*)(w3 + kk);
            a0 = fmaf(xv.x, v0.x, fmaf(xv.y, v0.y, fmaf(xv.z, v0.z, fmaf(xv.w, v0.w, a0))));
            a1 = fmaf(xv.x, v1.x, fmaf(xv.y, v1.y, fmaf(xv.z, v1.z, fmaf(xv.w, v1.w, a1))));
            a2 = fmaf(xv.x, v2.x, fmaf(xv.y, v2.y, fmaf(xv.z, v2.z, fmaf(xv.w, v2.w, a2))));
            a3 = fmaf(xv.x, v3.x, fmaf(xv.y, v3.y, fmaf(xv.z, v3.z, fmaf(xv.w, v3.w, a3))));
        }
    }
    if (t > 0) {
        const float* hrow = out + ((size_t)b * T_ + (t - 1)) * H_ + k0;
        const float* w0 = Wh + (size_t)(0 * H_ + j) * H_ + k0;
        const float* w1 = Wh + (size_t)(1 * H_ + j) * H_ + k0;
        const float* w2 = Wh + (size_t)(2 * H_ + j) * H_ + k0;
        const float* w3 = Wh + (size_t)(3 * H_ + j) * H_ + k0;
        for (int kk = 0; kk < H_ / 2; kk += 4) {
            float4 hv = *(const float4*)(hrow + kk);
            float4 v0 = *(const float4*)(w0 + kk), v1 = *(const float4*)(w1 + kk);
            float4 v2 = *(const float4*)(w2 + kk), v3 = *(const float4*)(w3 + kk);
            a0 = fmaf(hv.x, v0.x, fmaf(hv.y, v0.y, fmaf(hv.z, v0.z, fmaf(hv.w, v0.w, a0))));
            a1 = fmaf(hv.x, v1.x, fmaf(hv.y, v1.y, fmaf(hv.z, v1.z, fmaf(hv.w, v1.w, a1))));
            a2 = fmaf(hv.x, v2.x, fmaf(hv.y, v2.y, fmaf(hv.z, v2.z, fmaf(hv.w, v2.w, a2))));
            a3 = fmaf(hv.x, v3.x, fmaf(hv.y, v3.y, fmaf(hv.z, v3.z, fmaf(hv.w, v3.w, a3))));
        }
    }
    a0 += __shfl_xor(a0, 1, 64); a1 += __shfl_xor(a1, 1, 64);
    a2 += __shfl_xor(a2, 1, 64); a3 += __shfl_xor(a3, 1, 64);
    if (khalf == 0) {
        float gi = sigm(a0 + bx[0 * H_ + j] + bh[0 * H_ + j]);
        float gf = sigm(a1 + bx[1 * H_ + j] + bh[1 * H_ + j]);
        float gg = sigm(a2 + bx[2 * H_ + j] + bh[2 * H_ + j]);
        float go = sigm(a3 + bx[3 * H_ + j] + bh[3 * H_ + j]);
        size_t ci = (size_t)b * H_ + j;
        float c = (t > 0) ? c_state[ci] : 0.0f;
        c = c * gf + gi * gg;
        c_state[ci] = c;
        out[((size_t)b * T_ + t) * H_ + j] = go * tanhf(c);
    }
}

extern "C" void kernel_launch(void* const* d_in, const int* in_sizes, int n_in,
                              void* d_out, int out_size, void* d_ws, size_t ws_size,
                              hipStream_t stream) {
    const float* inp = (const float*)d_in[0];
    const float* Wx  = (const float*)d_in[1];
    const float* bx  = (const float*)d_in[2];
    const float* Wh  = (const float*)d_in[3];
    const float* bh  = (const float*)d_in[4];
    float* out = (float*)d_out;
    char* ws = (char*)d_ws;

    if (ws_size < WS_NEEDED) {
        float* c_state = (float*)d_ws;
        for (int t = 0; t < T_; ++t)
            lstm_step<<<dim3(H_ / 4), dim3(256), 0, stream>>>(inp, Wx, bx, Wh, bh, out, c_state, t);
        return;
    }

    unsigned int*    flags = (unsigned int*)(ws + OFF_FLG);
    __hip_bfloat16*  Whb   = (__hip_bfloat16*)(ws + OFF_WHB);
    __hip_bfloat16*  Wxb   = (__hip_bfloat16*)(ws + OFF_WXB);
    __hip_bfloat16*  inp_b = (__hip_bfloat16*)(ws + OFF_INPB);  // becomes hseq after xg_gemm
    float*           bxh   = (float*)(ws + OFF_BXH);
    __hip_bfloat16*  xg    = (__hip_bfloat16*)(ws + OFF_XG);
    __hip_bfloat16*  hseq  = inp_b;

    hipMemsetAsync(flags, 0, 4096, stream);

    convert_all<<<dim3(4096), dim3(256), 0, stream>>>(inp, Wx, bx, Wh, bh, inp_b, Wxb, Whb, bxh);

    xg_gemm<<<dim3(BT / 128, G4 / 128), dim3(256), 0, stream>>>(inp_b, Wxb, bxh, xg);

    lstm_scan<<<dim3(NWG), dim3(512), 0, stream>>>(xg, Whb, out, hseq, flags);
}

// Round 11
// 2595.900 us; speedup vs baseline: 2.3120x; 2.3120x over previous
//
#include <hip/hip_runtime.h>
#include <hip/hip_bf16.h>
#include <math.h>

#define B_ 32
#define T_ 512
#define D_ 1024
#define H_ 1024
#define G4 4096
#define BT 16384
#define NWG 64

using bf16x8 = __attribute__((ext_vector_type(8))) short;
using f32x4  = __attribute__((ext_vector_type(4))) float;
typedef unsigned long long u64;
typedef unsigned int u32;

__device__ __forceinline__ float sigm(float x) { return 1.0f / (1.0f + __expf(-x)); }

// ---- workspace layout (bytes) ----
#define OFF_FLG   0ull                          // 64 flags, 64B stride = 4096
#define OFF_WHB   4096ull                       // Wh bf16 [4096][1024] = 8388608
#define OFF_WXB   (OFF_WHB + 8388608ull)        // Wx bf16 = 8388608
#define OFF_INPB  (OFF_WXB + 8388608ull)        // inp bf16 (reused as hseq[T][B][H]) = 33554432
#define OFF_BXH   (OFF_INPB + 33554432ull)      // bx+bh f32 [4096] = 16384
#define OFF_XG    (OFF_BXH + 16384ull)          // xg bf16 [T][NWG][4][32][16] = 134217728
#define WS_NEEDED (OFF_XG + 134217728ull)

// scan LDS: [0,65536) h-stage 32x2048B swizzled  (no gbuf — gates combine in-wave)
#define SMEM_TOTAL  65536

// ============ phase 1: convert inputs to bf16, fold biases ============
__global__ __launch_bounds__(256) void convert_all(
    const float* __restrict__ inp, const float* __restrict__ Wx,
    const float* __restrict__ bx, const float* __restrict__ Wh,
    const float* __restrict__ bh,
    __hip_bfloat16* __restrict__ inp_b, __hip_bfloat16* __restrict__ Wx_b,
    __hip_bfloat16* __restrict__ Wh_b, float* __restrict__ bxh)
{
    const int gid = blockIdx.x * 256 + threadIdx.x;   // 0 .. 1048575
    {
        const float4* s = (const float4*)inp + (size_t)gid * 4;
        #pragma unroll
        for (int v = 0; v < 4; ++v) {
            float4 f = s[v];
            size_t base = (size_t)gid * 16 + v * 4;
            inp_b[base + 0] = __float2bfloat16(f.x);
            inp_b[base + 1] = __float2bfloat16(f.y);
            inp_b[base + 2] = __float2bfloat16(f.z);
            inp_b[base + 3] = __float2bfloat16(f.w);
        }
    }
    {
        float4 fx = ((const float4*)Wx)[gid];
        float4 fh = ((const float4*)Wh)[gid];
        size_t base = (size_t)gid * 4;
        Wx_b[base + 0] = __float2bfloat16(fx.x);
        Wx_b[base + 1] = __float2bfloat16(fx.y);
        Wx_b[base + 2] = __float2bfloat16(fx.z);
        Wx_b[base + 3] = __float2bfloat16(fx.w);
        Wh_b[base + 0] = __float2bfloat16(fh.x);
        Wh_b[base + 1] = __float2bfloat16(fh.y);
        Wh_b[base + 2] = __float2bfloat16(fh.z);
        Wh_b[base + 3] = __float2bfloat16(fh.w);
    }
    if (gid < G4) bxh[gid] = bx[gid] + bh[gid];
}

// ============ phase 2: xg = X @ Wx^T + (bx+bh)  (128x128 LDS-staged, T2 swizzle) ============
__global__ __launch_bounds__(256) void xg_gemm(
    const __hip_bfloat16* __restrict__ X,    // [BT][D], row = b*T + t
    const __hip_bfloat16* __restrict__ Wxb,  // [G4][D]
    const float* __restrict__ bxh,           // [G4]
    __hip_bfloat16* __restrict__ xg)         // [T][NWG][4][32][16]
{
    __shared__ __align__(16) char As[16384];
    __shared__ __align__(16) char Bs[16384];

    const int m0 = blockIdx.x * 128;
    const int n0 = blockIdx.y * 128;
    const int tid = threadIdx.x;
    const int lane = tid & 63;
    const int wv = tid >> 6;              // 0..3
    const int vr = wv >> 1, vc = wv & 1;  // 64x64 quadrant
    const int l15 = lane & 15;
    const int kg = (lane >> 4) * 8;

    const int srow_ = wv * 32 + (lane >> 3);
    const int scolb = (lane & 7) * 16;

    f32x4 acc[4][4] = {};

    for (int k0 = 0; k0 < D_; k0 += 64) {
        #pragma unroll
        for (int c = 0; c < 4; ++c) {
            const int row = srow_ + c * 8;
            const int cb  = scolb ^ ((row & 7) << 4);
            const char* ga = (const char*)X   + (size_t)(m0 + row) * 2048 + k0 * 2 + cb;
            const char* gb = (const char*)Wxb + (size_t)(n0 + row) * 2048 + k0 * 2 + cb;
            __builtin_amdgcn_global_load_lds(
                (const __attribute__((address_space(1))) void*)ga,
                (__attribute__((address_space(3))) void*)(As + wv * 4096 + c * 1024),
                16, 0, 0);
            __builtin_amdgcn_global_load_lds(
                (const __attribute__((address_space(1))) void*)gb,
                (__attribute__((address_space(3))) void*)(Bs + wv * 4096 + c * 1024),
                16, 0, 0);
        }
        __syncthreads();

        #pragma unroll
        for (int kk = 0; kk < 64; kk += 32) {
            bf16x8 af[4], bf[4];
            #pragma unroll
            for (int mi = 0; mi < 4; ++mi) {
                const int row = vr * 64 + mi * 16 + l15;
                af[mi] = *(const bf16x8*)(As + row * 128 + (((kk + kg) * 2) ^ ((row & 7) << 4)));
            }
            #pragma unroll
            for (int ni = 0; ni < 4; ++ni) {
                const int col = vc * 64 + ni * 16 + l15;
                bf[ni] = *(const bf16x8*)(Bs + col * 128 + (((kk + kg) * 2) ^ ((col & 7) << 4)));
            }
            #pragma unroll
            for (int mi = 0; mi < 4; ++mi)
                #pragma unroll
                for (int ni = 0; ni < 4; ++ni)
                    acc[mi][ni] = __builtin_amdgcn_mfma_f32_16x16x32_bf16(
                        af[mi], bf[ni], acc[mi][ni], 0, 0, 0);
        }
        __syncthreads();
    }

    #pragma unroll
    for (int ni = 0; ni < 4; ++ni) {
        const int col = n0 + vc * 64 + ni * 16 + l15;
        const int qq = col >> 10, ww = (col >> 4) & 63, jj = col & 15;
        const float bias = bxh[col];
        #pragma unroll
        for (int mi = 0; mi < 4; ++mi) {
            const int r0 = m0 + vr * 64 + mi * 16 + ((lane >> 4) << 2);
            #pragma unroll
            for (int r = 0; r < 4; ++r) {
                const int row = r0 + r;                 // = b*T + t
                const int bb = row >> 9, tt = row & 511;
                xg[(((size_t)tt * NWG + ww) * 4 + qq) * 512 + bb * 16 + jj] =
                    __float2bfloat16(acc[mi][ni][r] + bias);
            }
        }
    }
}

// ============ phase 3: persistent recurrent scan — hybrid (r7 staging + r10 gates) ============
// 64 WGs x 512 threads. Wave = (mwave, jg). B-frag row = gate col q*1024+w*16+jg*4+j4
// (q=l15>>2, j4=l15&3): each wave's C tile holds all 4 gates for 4 h-cols x 16 batches,
// so gates combine in-register via shfl_xor(4/8/12) — no gbuf, no gbuf barrier.
// A-frags from cooperative coalesced h-stage in swizzled LDS (round-7 path).
// Sync: wave0 polls 64 flags -> barrier; publish -> vmcnt(0) -> barrier -> flag.
__global__ __launch_bounds__(512) void lstm_scan(
    const __hip_bfloat16* __restrict__ xg,    // [T][NWG][4][32][16] (bias folded)
    const __hip_bfloat16* __restrict__ Whb,   // [G4][H]
    float* __restrict__ out,                  // [B][T][H] f32
    __hip_bfloat16* __restrict__ hseq,        // [T][B][H]
    unsigned int* __restrict__ flags)         // [NWG] at 64B stride
{
    extern __shared__ char smem[];            // h-stage: 32 rows x 2048B, XOR-swizzled

    const int w    = blockIdx.x;
    const int tid  = threadIdx.x;
    const int lane = tid & 63;
    const int wave = tid >> 6;
    const int mwave = wave >> 2;       // 0..1  (batch half)
    const int jg    = wave & 3;        // 4-col group
    const int l15   = lane & 15;
    const int hi    = lane >> 4;       // 0..3
    const int kg    = hi * 8;          // k-octet (elements)
    const int q     = l15 >> 2;        // gate index of this lane's B column
    const int j4    = l15 & 3;         // col within group

    // ---- pin Wh B-fragments: row = gate col q*1024 + w*16 + jg*4 + j4 ----
    bf16x8 bfrag[32];
    {
        const char* wrow = (const char*)(Whb + (size_t)(q * 1024 + w * 16 + jg * 4 + j4) * H_);
        #pragma unroll
        for (int i = 0; i < 32; ++i) {
            u64 lo = __hip_atomic_load((const u64*)(wrow + (i * 32 + kg) * 2),
                                       __ATOMIC_RELAXED, __HIP_MEMORY_SCOPE_AGENT);
            u64 hi_ = __hip_atomic_load((const u64*)(wrow + (i * 32 + kg) * 2 + 8),
                                        __ATOMIC_RELAXED, __HIP_MEMORY_SCOPE_AGENT);
            union { u64 qv[2]; bf16x8 v; } u;
            u.qv[0] = lo; u.qv[1] = hi_;
            bfrag[i] = u.v;
        }
    }

    const int dbr  = mwave * 16 + hi * 4;          // batch base of this lane's C rows
    const int jcol = w * 16 + jg * 4 + j4;         // h column this lane publishes
    const int pbb  = dbr + q;                      // batch this lane publishes (r = q)
    float cst[4] = {0.f, 0.f, 0.f, 0.f};           // c state for (dbr+r, jcol)

    // A-frag LDS addressing (row = batch = mwave*16 + l15)
    const int arow  = mwave * 16 + l15;
    const int abase = arow * 2048;
    const int axor  = (arow & 7) << 4;
    // staging ownership: quarter-wave per row
    const int srow  = wave * 4 + hi;               // 0..31
    const int ql    = lane & 15;

    for (int t = 0; t < T_; ++t) {
        // xg prefetch (independent of h; in flight during the wait)
        float xgv[4];
        {
            const size_t sbase = (((size_t)t * NWG + w) * 4 + q) * 512;
            #pragma unroll
            for (int r = 0; r < 4; ++r)
                xgv[r] = __bfloat162float(xg[sbase + (dbr + r) * 16 + (jg * 4 + j4)]);
        }

        f32x4 acc = {};
        if (t > 0) {
            // ---- arrival: wave0's 64 lanes poll the 64 flags; barrier releases all ----
            if (wave == 0) {
                const unsigned int* fp = flags + lane * 16;
                while (__hip_atomic_load(fp, __ATOMIC_RELAXED, __HIP_MEMORY_SCOPE_AGENT)
                       < (unsigned)t)
                    __builtin_amdgcn_s_sleep(1);
            }
            __syncthreads();   // (P)

            // ---- stage h_{t-1} into LDS (coalesced 16B loads, XOR-swizzled writes) ----
            {
                const bf16x8* src = (const bf16x8*)(hseq + ((size_t)(t - 1) * B_ + srow) * H_);
                #pragma unroll
                for (int j = 0; j < 8; ++j) {
                    bf16x8 v = src[ql + j * 16];
                    *(bf16x8*)(smem + srow * 2048 + (((ql + j * 16) * 16) ^ ((srow & 7) << 4))) = v;
                }
            }
            __syncthreads();   // (A)

            // ---- 32 MFMAs, 4 accumulation chains, A from LDS, B from registers ----
            f32x4 a0 = {}, a1 = {}, a2 = {}, a3 = {};
            #pragma unroll
            for (int i = 0; i < 8; ++i) {
                bf16x8 v0 = *(const bf16x8*)(smem + abase + ((((4 * i + 0) * 64) + kg * 2) ^ axor));
                bf16x8 v1 = *(const bf16x8*)(smem + abase + ((((4 * i + 1) * 64) + kg * 2) ^ axor));
                bf16x8 v2 = *(const bf16x8*)(smem + abase + ((((4 * i + 2) * 64) + kg * 2) ^ axor));
                bf16x8 v3 = *(const bf16x8*)(smem + abase + ((((4 * i + 3) * 64) + kg * 2) ^ axor));
                a0 = __builtin_amdgcn_mfma_f32_16x16x32_bf16(v0, bfrag[4 * i + 0], a0, 0, 0, 0);
                a1 = __builtin_amdgcn_mfma_f32_16x16x32_bf16(v1, bfrag[4 * i + 1], a1, 0, 0, 0);
                a2 = __builtin_amdgcn_mfma_f32_16x16x32_bf16(v2, bfrag[4 * i + 2], a2, 0, 0, 0);
                a3 = __builtin_amdgcn_mfma_f32_16x16x32_bf16(v3, bfrag[4 * i + 3], a3, 0, 0, 0);
            }
            acc = (a0 + a1) + (a2 + a3);
        }

        // ---- in-wave gate combine + pointwise (4x redundant across q-lanes) ----
        float h4[4];
        #pragma unroll
        for (int r = 0; r < 4; ++r) {
            float v  = acc[r] + xgv[r];
            float xb = __shfl_xor(v, 4, 64);
            float xc = __shfl_xor(v, 8, 64);
            float xd = __shfl_xor(v, 12, 64);
            float g0 = (q == 0) ? v : (q == 1) ? xb : (q == 2) ? xc : xd;
            float g1 = (q == 1) ? v : (q == 0) ? xb : (q == 3) ? xc : xd;
            float g2 = (q == 2) ? v : (q == 3) ? xb : (q == 0) ? xc : xd;
            float g3 = (q == 3) ? v : (q == 2) ? xb : (q == 1) ? xc : xd;
            float gi = sigm(g0), gf = sigm(g1), gg = sigm(g2), go = sigm(g3);
            cst[r] = cst[r] * gf + gi * gg;
            h4[r] = go * tanhf(cst[r]);
        }

        // ---- publish h (lane's r=q cell), shfl-pack 4 cols -> one u64 UC store ----
        float hpub = (q == 0) ? h4[0] : (q == 1) ? h4[1] : (q == 2) ? h4[2] : h4[3];
        {
            __hip_bfloat16 hb = __float2bfloat16(hpub);
            unsigned short hs_;
            __builtin_memcpy(&hs_, &hb, 2);
            u32 hu = hs_;
            u32 x1 = __shfl_xor(hu, 1, 64);
            u32 lo = hu | (x1 << 16);              // valid on even j4
            u32 x2 = __shfl_xor(lo, 2, 64);
            if (j4 == 0) {
                u64 val = (u64)lo | ((u64)x2 << 32);
                u64* dst = (u64*)(hseq + ((size_t)t * B_ + pbb) * H_ + w * 16 + jg * 4);
                __hip_atomic_store(dst, val, __ATOMIC_RELAXED, __HIP_MEMORY_SCOPE_AGENT);
            }
        }
        asm volatile("s_waitcnt vmcnt(0)" ::: "memory");  // wave's h stores acked
        __syncthreads();   // (C) all waves' stores acked
        if (tid == 0 && t < T_ - 1)
            __hip_atomic_store(flags + w * 16, (unsigned)(t + 1),
                               __ATOMIC_RELAXED, __HIP_MEMORY_SCOPE_AGENT);

        out[((size_t)pbb * T_ + t) * H_ + jcol] = hpub;   // f32 out, shadow time
    }
}

// ============ fallback (round-1 slow path) if ws too small ============
__global__ __launch_bounds__(256) void lstm_step(
    const float* __restrict__ inp, const float* __restrict__ Wx,
    const float* __restrict__ bx, const float* __restrict__ Wh,
    const float* __restrict__ bh, float* __restrict__ out,
    float* __restrict__ c_state, int t)
{
    const int tid = threadIdx.x;
    const int lane = tid & 63;
    const int khalf = lane & 1;
    const int b = lane >> 1;
    const int j = blockIdx.x * 4 + (tid >> 6);
    const int k0 = khalf * (D_ / 2);
    float a0 = 0.f, a1 = 0.f, a2 = 0.f, a3 = 0.f;
    {
        const float* xrow = inp + ((size_t)b * T_ + t) * D_ + k0;
        const float* w0 = Wx + (size_t)(0 * H_ + j) * D_ + k0;
        const float* w1 = Wx + (size_t)(1 * H_ + j) * D_ + k0;
        const float* w2 = Wx + (size_t)(2 * H_ + j) * D_ + k0;
        const float* w3 = Wx + (size_t)(3 * H_ + j) * D_ + k0;
        for (int kk = 0; kk < D_ / 2; kk += 4) {
            float4 xv = *(const float4*)(xrow + kk);
            float4 v0 = *(const float4*)(w0 + kk), v1 = *(const float4*)(w1 + kk);
            float4 v2 = *(const float4*)(w2 + kk), v3 = *(const float4*)(w3 + kk);
            a0 = fmaf(xv.x, v0.x, fmaf(xv.y, v0.y, fmaf(xv.z, v0.z, fmaf(xv.w, v0.w, a0))));
            a1 = fmaf(xv.x, v1.x, fmaf(xv.y, v1.y, fmaf(xv.z, v1.z, fmaf(xv.w, v1.w, a1))));
            a2 = fmaf(xv.x, v2.x, fmaf(xv.y, v2.y, fmaf(xv.z, v2.z, fmaf(xv.w, v2.w, a2))));
            a3 = fmaf(xv.x, v3.x, fmaf(xv.y, v3.y, fmaf(xv.z, v3.z, fmaf(xv.w, v3.w, a3))));
        }
    }
    if (t > 0) {
        const float* hrow = out + ((size_t)b * T_ + (t - 1)) * H_ + k0;
        const float* w0 = Wh + (size_t)(0 * H_ + j) * H_ + k0;
        const float* w1 = Wh + (size_t)(1 * H_ + j) * H_ + k0;
        const float* w2 = Wh + (size_t)(2 * H_ + j) * H_ + k0;
        const float* w3 = Wh + (size_t)(3 * H_ + j) * H_ + k0;
        for (int kk = 0; kk < H_ / 2; kk += 4) {
            float4 hv = *(const float4*)(hrow + kk);
            float4 v0 = *(const float4*)(w0 + kk), v1 = *(const float4*)(w1 + kk);
            float4 v2 = *(const float4*)(w2 + kk), v3 = *(const float4*)(w3 + kk);
            a0 = fmaf(hv.x, v0.x, fmaf(hv.y, v0.y, fmaf(hv.z, v0.z, fmaf(hv.w, v0.w, a0))));
            a1 = fmaf(hv.x, v1.x, fmaf(hv.y, v1.y, fmaf(hv.z, v1.z, fmaf(hv.w, v1.w, a1))));
            a2 = fmaf(hv.x, v2.x, fmaf(hv.y, v2.y, fmaf(hv.z, v2.z, fmaf(hv.w, v2.w, a2))));
            a3 = fmaf(hv.x, v3.x, fmaf(hv.y, v3.y, fmaf(hv.z, v3.z, fmaf(hv.w, v3.w, a3))));
        }
    }
    a0 += __shfl_xor(a0, 1, 64); a1 += __shfl_xor(a1, 1, 64);
    a2 += __shfl_xor(a2, 1, 64); a3 += __shfl_xor(a3, 1, 64);
    if (khalf == 0) {
        float gi = sigm(a0 + bx[0 * H_ + j] + bh[0 * H_ + j]);
        float gf = sigm(a1 + bx[1 * H_ + j] + bh[1 * H_ + j]);
        float gg = sigm(a2 + bx[2 * H_ + j] + bh[2 * H_ + j]);
        float go = sigm(a3 + bx[3 * H_ + j] + bh[3 * H_ + j]);
        size_t ci = (size_t)b * H_ + j;
        float c = (t > 0) ? c_state[ci] : 0.0f;
        c = c * gf + gi * gg;
        c_state[ci] = c;
        out[((size_t)b * T_ + t) * H_ + j] = go * tanhf(c);
    }
}

extern "C" void kernel_launch(void* const* d_in, const int* in_sizes, int n_in,
                              void* d_out, int out_size, void* d_ws, size_t ws_size,
                              hipStream_t stream) {
    const float* inp = (const float*)d_in[0];
    const float* Wx  = (const float*)d_in[1];
    const float* bx  = (const float*)d_in[2];
    const float* Wh  = (const float*)d_in[3];
    const float* bh  = (const float*)d_in[4];
    float* out = (float*)d_out;
    char* ws = (char*)d_ws;

    if (ws_size < WS_NEEDED) {
        float* c_state = (float*)d_ws;
        for (int t = 0; t < T_; ++t)
            lstm_step<<<dim3(H_ / 4), dim3(256), 0, stream>>>(inp, Wx, bx, Wh, bh, out, c_state, t);
        return;
    }

    unsigned int*    flags = (unsigned int*)(ws + OFF_FLG);
    __hip_bfloat16*  Whb   = (__hip_bfloat16*)(ws + OFF_WHB);
    __hip_bfloat16*  Wxb   = (__hip_bfloat16*)(ws + OFF_WXB);
    __hip_bfloat16*  inp_b = (__hip_bfloat16*)(ws + OFF_INPB);  // becomes hseq after xg_gemm
    float*           bxh   = (float*)(ws + OFF_BXH);
    __hip_bfloat16*  xg    = (__hip_bfloat16*)(ws + OFF_XG);
    __hip_bfloat16*  hseq  = inp_b;

    hipMemsetAsync(flags, 0, 4096, stream);

    convert_all<<<dim3(4096), dim3(256), 0, stream>>>(inp, Wx, bx, Wh, bh, inp_b, Wxb, Whb, bxh);

    xg_gemm<<<dim3(BT / 128, G4 / 128), dim3(256), 0, stream>>>(inp_b, Wxb, bxh, xg);

    lstm_scan<<<dim3(NWG), dim3(512), SMEM_TOTAL, stream>>>(xg, Whb, out, hseq, flags);
}

// Round 12
// 2087.956 us; speedup vs baseline: 2.8744x; 1.2433x over previous
//
#include <hip/hip_runtime.h>
#include <hip/hip_bf16.h>
#include <math.h>

#define B_ 32
#define T_ 512
#define D_ 1024
#define H_ 1024
#define G4 4096
#define BT 16384
#define NWG 64

using bf16x8 = __attribute__((ext_vector_type(8))) short;
using f32x4  = __attribute__((ext_vector_type(4))) float;
typedef unsigned long long u64;
typedef unsigned int u32;

__device__ __forceinline__ float sigm(float x) { return 1.0f / (1.0f + __expf(-x)); }

// ---- workspace layout (bytes) ----
#define OFF_FLG   0ull                          // 64 flags, 64B stride = 4096
#define OFF_WHB   4096ull                       // Wh bf16 [4096][1024] = 8388608
#define OFF_WXB   (OFF_WHB + 8388608ull)        // Wx bf16 = 8388608
#define OFF_INPB  (OFF_WXB + 8388608ull)        // inp bf16 (reused as hseq[T][B][H]) = 33554432
#define OFF_BXH   (OFF_INPB + 33554432ull)      // bx+bh f32 [4096] = 16384
#define OFF_XG    (OFF_BXH + 16384ull)          // xg bf16 [T][NWG][4][32][16] = 134217728
#define WS_NEEDED (OFF_XG + 134217728ull)

// scan LDS: [0,65536) h-stage 32x2048B swizzled; [65536,74240) gbuf [32][4][17] f32;
// [74240,74304) lds_cnt
#define SMEM_GBUF   65536
#define SMEM_CNT    74240
#define SMEM_TOTAL  74304

// ============ phase 1: convert inputs to bf16, fold biases ============
__global__ __launch_bounds__(256) void convert_all(
    const float* __restrict__ inp, const float* __restrict__ Wx,
    const float* __restrict__ bx, const float* __restrict__ Wh,
    const float* __restrict__ bh,
    __hip_bfloat16* __restrict__ inp_b, __hip_bfloat16* __restrict__ Wx_b,
    __hip_bfloat16* __restrict__ Wh_b, float* __restrict__ bxh)
{
    const int gid = blockIdx.x * 256 + threadIdx.x;   // 0 .. 1048575
    {
        const float4* s = (const float4*)inp + (size_t)gid * 4;
        #pragma unroll
        for (int v = 0; v < 4; ++v) {
            float4 f = s[v];
            size_t base = (size_t)gid * 16 + v * 4;
            inp_b[base + 0] = __float2bfloat16(f.x);
            inp_b[base + 1] = __float2bfloat16(f.y);
            inp_b[base + 2] = __float2bfloat16(f.z);
            inp_b[base + 3] = __float2bfloat16(f.w);
        }
    }
    {
        float4 fx = ((const float4*)Wx)[gid];
        float4 fh = ((const float4*)Wh)[gid];
        size_t base = (size_t)gid * 4;
        Wx_b[base + 0] = __float2bfloat16(fx.x);
        Wx_b[base + 1] = __float2bfloat16(fx.y);
        Wx_b[base + 2] = __float2bfloat16(fx.z);
        Wx_b[base + 3] = __float2bfloat16(fx.w);
        Wh_b[base + 0] = __float2bfloat16(fh.x);
        Wh_b[base + 1] = __float2bfloat16(fh.y);
        Wh_b[base + 2] = __float2bfloat16(fh.z);
        Wh_b[base + 3] = __float2bfloat16(fh.w);
    }
    if (gid < G4) bxh[gid] = bx[gid] + bh[gid];
}

// ============ phase 2: xg = X @ Wx^T + (bx+bh)  (128x128 LDS-staged, T2 swizzle) ============
__global__ __launch_bounds__(256) void xg_gemm(
    const __hip_bfloat16* __restrict__ X,    // [BT][D], row = b*T + t
    const __hip_bfloat16* __restrict__ Wxb,  // [G4][D]
    const float* __restrict__ bxh,           // [G4]
    __hip_bfloat16* __restrict__ xg)         // [T][NWG][4][32][16]
{
    __shared__ __align__(16) char As[16384];
    __shared__ __align__(16) char Bs[16384];

    const int m0 = blockIdx.x * 128;
    const int n0 = blockIdx.y * 128;
    const int tid = threadIdx.x;
    const int lane = tid & 63;
    const int wv = tid >> 6;              // 0..3
    const int vr = wv >> 1, vc = wv & 1;  // 64x64 quadrant
    const int l15 = lane & 15;
    const int kg = (lane >> 4) * 8;

    const int srow_ = wv * 32 + (lane >> 3);
    const int scolb = (lane & 7) * 16;

    f32x4 acc[4][4] = {};

    for (int k0 = 0; k0 < D_; k0 += 64) {
        #pragma unroll
        for (int c = 0; c < 4; ++c) {
            const int row = srow_ + c * 8;
            const int cb  = scolb ^ ((row & 7) << 4);
            const char* ga = (const char*)X   + (size_t)(m0 + row) * 2048 + k0 * 2 + cb;
            const char* gb = (const char*)Wxb + (size_t)(n0 + row) * 2048 + k0 * 2 + cb;
            __builtin_amdgcn_global_load_lds(
                (const __attribute__((address_space(1))) void*)ga,
                (__attribute__((address_space(3))) void*)(As + wv * 4096 + c * 1024),
                16, 0, 0);
            __builtin_amdgcn_global_load_lds(
                (const __attribute__((address_space(1))) void*)gb,
                (__attribute__((address_space(3))) void*)(Bs + wv * 4096 + c * 1024),
                16, 0, 0);
        }
        __syncthreads();

        #pragma unroll
        for (int kk = 0; kk < 64; kk += 32) {
            bf16x8 af[4], bf[4];
            #pragma unroll
            for (int mi = 0; mi < 4; ++mi) {
                const int row = vr * 64 + mi * 16 + l15;
                af[mi] = *(const bf16x8*)(As + row * 128 + (((kk + kg) * 2) ^ ((row & 7) << 4)));
            }
            #pragma unroll
            for (int ni = 0; ni < 4; ++ni) {
                const int col = vc * 64 + ni * 16 + l15;
                bf[ni] = *(const bf16x8*)(Bs + col * 128 + (((kk + kg) * 2) ^ ((col & 7) << 4)));
            }
            #pragma unroll
            for (int mi = 0; mi < 4; ++mi)
                #pragma unroll
                for (int ni = 0; ni < 4; ++ni)
                    acc[mi][ni] = __builtin_amdgcn_mfma_f32_16x16x32_bf16(
                        af[mi], bf[ni], acc[mi][ni], 0, 0, 0);
        }
        __syncthreads();
    }

    #pragma unroll
    for (int ni = 0; ni < 4; ++ni) {
        const int col = n0 + vc * 64 + ni * 16 + l15;
        const int qq = col >> 10, ww = (col >> 4) & 63, jj = col & 15;
        const float bias = bxh[col];
        #pragma unroll
        for (int mi = 0; mi < 4; ++mi) {
            const int r0 = m0 + vr * 64 + mi * 16 + ((lane >> 4) << 2);
            #pragma unroll
            for (int r = 0; r < 4; ++r) {
                const int row = r0 + r;                 // = b*T + t
                const int bb = row >> 9, tt = row & 511;
                xg[(((size_t)tt * NWG + ww) * 4 + qq) * 512 + bb * 16 + jj] =
                    __float2bfloat16(acc[mi][ni][r] + bias);
            }
        }
    }
}

// ============ phase 3: persistent recurrent scan (r7 structure + decoupled publish) ============
// 64 WGs x 512 threads, wave = (mwave, q) as in round 7 (champion, 1710us).
// Changes vs r7: (1) barrier-P poll release instead of LDS relay; (2) per-wave register
// publish (16 u64 UC stores) + parallel vmcnt(0) + LDS arrival counter; wave0 spins on
// counter then publishes the WG flag — waves 1-7 run ahead into the next step's xg
// prefetch; (3) f32 out written here in shadow time (expand kernel deleted).
__global__ __launch_bounds__(512) void lstm_scan(
    const __hip_bfloat16* __restrict__ xg,    // [T][NWG][4][32][16] (bias folded)
    const __hip_bfloat16* __restrict__ Whb,   // [G4][H]
    float* __restrict__ out,                  // [B][T][H] f32
    __hip_bfloat16* __restrict__ hseq,        // [T][B][H]
    unsigned int* __restrict__ flags)         // [NWG] at 64B stride
{
    extern __shared__ char smem[];
    float* gbuf = (float*)(smem + SMEM_GBUF);
    int* lds_cnt = (int*)(smem + SMEM_CNT);

    const int w    = blockIdx.x;
    const int tid  = threadIdx.x;
    const int lane = tid & 63;
    const int wave = tid >> 6;
    const int mwave = wave >> 2;
    const int q     = wave & 3;
    const int l15   = lane & 15;
    const int kg    = (lane >> 4) * 8;

    if (tid == 0) *lds_cnt = 0;

    // ---- pin this wave's Wh B-fragments (UC loads; land in AGPRs) ----
    bf16x8 bfrag[32];
    {
        const char* wrow = (const char*)(Whb + (size_t)(q * 1024 + w * 16 + l15) * H_);
        #pragma unroll
        for (int i = 0; i < 32; ++i) {
            u64 lo = __hip_atomic_load((const u64*)(wrow + (i * 32 + kg) * 2),
                                       __ATOMIC_RELAXED, __HIP_MEMORY_SCOPE_AGENT);
            u64 hi = __hip_atomic_load((const u64*)(wrow + (i * 32 + kg) * 2 + 8),
                                       __ATOMIC_RELAXED, __HIP_MEMORY_SCOPE_AGENT);
            union { u64 qv[2]; bf16x8 v; } u;
            u.qv[0] = lo; u.qv[1] = hi;
            bfrag[i] = u.v;
        }
    }

    const int pb  = tid >> 4;          // batch 0..31 (pjj == l15)
    const int jcol = w * 16 + l15;     // h column this thread owns pointwise
    float cst = 0.0f;

    const int dbr   = mwave * 16 + ((lane >> 4) << 2);
    const int arow  = mwave * 16 + l15;
    const int abase = arow * 2048;
    const int axor  = (arow & 7) << 4;
    const int srow  = wave * 4 + (lane >> 4);           // staging row 0..31
    const int ql    = lane & 15;

    for (int t = 0; t < T_; ++t) {
        // xg prefetch (independent of h; in flight during the wait)
        float xgv[4];
        {
            const size_t sbase = (((size_t)t * NWG + w) * 4 + q) * 512;
            #pragma unroll
            for (int r = 0; r < 4; ++r)
                xgv[r] = __bfloat162float(xg[sbase + (dbr + r) * 16 + l15]);
        }

        f32x4 acc = {};
        if (t > 0) {
            // ---- arrival: wave0's 64 lanes poll the 64 flags; barrier releases all ----
            if (wave == 0) {
                const unsigned int* fp = flags + lane * 16;
                while (__hip_atomic_load(fp, __ATOMIC_RELAXED, __HIP_MEMORY_SCOPE_AGENT)
                       < (unsigned)t)
                    __builtin_amdgcn_s_sleep(1);
            }
            __syncthreads();   // (P)

            // ---- stage h_{t-1} into LDS (plain 16B loads, XOR-swizzled writes) ----
            {
                const bf16x8* src = (const bf16x8*)(hseq + ((size_t)(t - 1) * B_ + srow) * H_);
                #pragma unroll
                for (int j = 0; j < 8; ++j) {
                    bf16x8 v = src[ql + j * 16];
                    *(bf16x8*)(smem + srow * 2048 + (((ql + j * 16) * 16) ^ ((srow & 7) << 4))) = v;
                }
            }
            __syncthreads();   // (A)

            // ---- 32 MFMAs, 4 accumulation chains ----
            f32x4 a0 = {}, a1 = {}, a2 = {}, a3 = {};
            #pragma unroll
            for (int i = 0; i < 8; ++i) {
                bf16x8 v0 = *(const bf16x8*)(smem + abase + ((((4 * i + 0) * 64) + kg * 2) ^ axor));
                bf16x8 v1 = *(const bf16x8*)(smem + abase + ((((4 * i + 1) * 64) + kg * 2) ^ axor));
                bf16x8 v2 = *(const bf16x8*)(smem + abase + ((((4 * i + 2) * 64) + kg * 2) ^ axor));
                bf16x8 v3 = *(const bf16x8*)(smem + abase + ((((4 * i + 3) * 64) + kg * 2) ^ axor));
                a0 = __builtin_amdgcn_mfma_f32_16x16x32_bf16(v0, bfrag[4 * i + 0], a0, 0, 0, 0);
                a1 = __builtin_amdgcn_mfma_f32_16x16x32_bf16(v1, bfrag[4 * i + 1], a1, 0, 0, 0);
                a2 = __builtin_amdgcn_mfma_f32_16x16x32_bf16(v2, bfrag[4 * i + 2], a2, 0, 0, 0);
                a3 = __builtin_amdgcn_mfma_f32_16x16x32_bf16(v3, bfrag[4 * i + 3], a3, 0, 0, 0);
            }
            acc = (a0 + a1) + (a2 + a3);
        }

        #pragma unroll
        for (int r = 0; r < 4; ++r)
            gbuf[((dbr + r) * 4 + q) * 17 + l15] = acc[r] + xgv[r];
        __syncthreads();   // (B)

        // ---- pointwise (thread = (pb, l15)); c stays in register ----
        float h;
        {
            float gi = sigm(gbuf[(pb * 4 + 0) * 17 + l15]);
            float gf = sigm(gbuf[(pb * 4 + 1) * 17 + l15]);
            float gg = sigm(gbuf[(pb * 4 + 2) * 17 + l15]);  // sigmoid cell gate, per reference
            float go = sigm(gbuf[(pb * 4 + 3) * 17 + l15]);
            cst = cst * gf + gi * gg;
            float e2 = __expf(2.0f * cst);                   // tanh(c) = 1 - 2/(e^{2c}+1)
            h = go * (1.0f - 2.0f / (e2 + 1.0f));
        }

        // ---- per-wave register publish: 16 u64 UC stores, parallel ack, counter ----
        if (t < T_ - 1) {
            __hip_bfloat16 hb = __float2bfloat16(h);
            unsigned short hs_;
            __builtin_memcpy(&hs_, &hb, 2);
            u32 hu = hs_;
            u32 h1 = __shfl_down(hu, 1, 64);
            u32 h2 = __shfl_down(hu, 2, 64);
            u32 h3 = __shfl_down(hu, 3, 64);
            if ((l15 & 3) == 0) {
                u64 val = (u64)(hu | (h1 << 16)) | (((u64)(h2 | (h3 << 16))) << 32);
                u64* dst = (u64*)(hseq + ((size_t)t * B_ + pb) * H_ + w * 16 + l15);
                __hip_atomic_store(dst, val, __ATOMIC_RELAXED, __HIP_MEMORY_SCOPE_AGENT);
            }
            asm volatile("s_waitcnt vmcnt(0)" ::: "memory");   // this wave's stores acked

            if (wave != 0) {
                if (lane == 0)
                    __hip_atomic_fetch_add(lds_cnt, 1, __ATOMIC_RELAXED,
                                           __HIP_MEMORY_SCOPE_WORKGROUP);
                // run ahead into next step's xg prefetch + barrier P
            } else {
                if (lane == 0) {
                    while (__hip_atomic_load(lds_cnt, __ATOMIC_RELAXED,
                                             __HIP_MEMORY_SCOPE_WORKGROUP) < 7 * (t + 1))
                        ;  // LDS spin, ~40cy period
                    __hip_atomic_store(flags + w * 16, (unsigned)(t + 1),
                                       __ATOMIC_RELAXED, __HIP_MEMORY_SCOPE_AGENT);
                }
            }
        }

        out[((size_t)pb * T_ + t) * H_ + jcol] = h;   // f32 out, shadow time
    }
}

// ============ fallback (round-1 slow path) if ws too small ============
__global__ __launch_bounds__(256) void lstm_step(
    const float* __restrict__ inp, const float* __restrict__ Wx,
    const float* __restrict__ bx, const float* __restrict__ Wh,
    const float* __restrict__ bh, float* __restrict__ out,
    float* __restrict__ c_state, int t)
{
    const int tid = threadIdx.x;
    const int lane = tid & 63;
    const int khalf = lane & 1;
    const int b = lane >> 1;
    const int j = blockIdx.x * 4 + (tid >> 6);
    const int k0 = khalf * (D_ / 2);
    float a0 = 0.f, a1 = 0.f, a2 = 0.f, a3 = 0.f;
    {
        const float* xrow = inp + ((size_t)b * T_ + t) * D_ + k0;
        const float* w0 = Wx + (size_t)(0 * H_ + j) * D_ + k0;
        const float* w1 = Wx + (size_t)(1 * H_ + j) * D_ + k0;
        const float* w2 = Wx + (size_t)(2 * H_ + j) * D_ + k0;
        const float* w3 = Wx + (size_t)(3 * H_ + j) * D_ + k0;
        for (int kk = 0; kk < D_ / 2; kk += 4) {
            float4 xv = *(const float4*)(xrow + kk);
            float4 v0 = *(const float4*)(w0 + kk), v1 = *(const float4*)(w1 + kk);
            float4 v2 = *(const float4*)(w2 + kk), v3 = *(const float4*)(w3 + kk);
            a0 = fmaf(xv.x, v0.x, fmaf(xv.y, v0.y, fmaf(xv.z, v0.z, fmaf(xv.w, v0.w, a0))));
            a1 = fmaf(xv.x, v1.x, fmaf(xv.y, v1.y, fmaf(xv.z, v1.z, fmaf(xv.w, v1.w, a1))));
            a2 = fmaf(xv.x, v2.x, fmaf(xv.y, v2.y, fmaf(xv.z, v2.z, fmaf(xv.w, v2.w, a2))));
            a3 = fmaf(xv.x, v3.x, fmaf(xv.y, v3.y, fmaf(xv.z, v3.z, fmaf(xv.w, v3.w, a3))));
        }
    }
    if (t > 0) {
        const float* hrow = out + ((size_t)b * T_ + (t - 1)) * H_ + k0;
        const float* w0 = Wh + (size_t)(0 * H_ + j) * H_ + k0;
        const float* w1 = Wh + (size_t)(1 * H_ + j) * H_ + k0;
        const float* w2 = Wh + (size_t)(2 * H_ + j) * H_ + k0;
        const float* w3 = Wh + (size_t)(3 * H_ + j) * H_ + k0;
        for (int kk = 0; kk < H_ / 2; kk += 4) {
            float4 hv = *(const float4*)(hrow + kk);
            float4 v0 = *(const float4*)(w0 + kk), v1 = *(const float4*)(w1 + kk);
            float4 v2 = *(const float4*)(w2 + kk), v3 = *(const float4*)(w3 + kk);
            a0 = fmaf(hv.x, v0.x, fmaf(hv.y, v0.y, fmaf(hv.z, v0.z, fmaf(hv.w, v0.w, a0))));
            a1 = fmaf(hv.x, v1.x, fmaf(hv.y, v1.y, fmaf(hv.z, v1.z, fmaf(hv.w, v1.w, a1))));
            a2 = fmaf(hv.x, v2.x, fmaf(hv.y, v2.y, fmaf(hv.z, v2.z, fmaf(hv.w, v2.w, a2))));
            a3 = fmaf(hv.x, v3.x, fmaf(hv.y, v3.y, fmaf(hv.z, v3.z, fmaf(hv.w, v3.w, a3))));
        }
    }
    a0 += __shfl_xor(a0, 1, 64); a1 += __shfl_xor(a1, 1, 64);
    a2 += __shfl_xor(a2, 1, 64); a3 += __shfl_xor(a3, 1, 64);
    if (khalf == 0) {
        float gi = sigm(a0 + bx[0 * H_ + j] + bh[0 * H_ + j]);
        float gf = sigm(a1 + bx[1 * H_ + j] + bh[1 * H_ + j]);
        float gg = sigm(a2 + bx[2 * H_ + j] + bh[2 * H_ + j]);
        float go = sigm(a3 + bx[3 * H_ + j] + bh[3 * H_ + j]);
        size_t ci = (size_t)b * H_ + j;
        float c = (t > 0) ? c_state[ci] : 0.0f;
        c = c * gf + gi * gg;
        c_state[ci] = c;
        out[((size_t)b * T_ + t) * H_ + j] = go * tanhf(c);
    }
}

extern "C" void kernel_launch(void* const* d_in, const int* in_sizes, int n_in,
                              void* d_out, int out_size, void* d_ws, size_t ws_size,
                              hipStream_t stream) {
    const float* inp = (const float*)d_in[0];
    const float* Wx  = (const float*)d_in[1];
    const float* bx  = (const float*)d_in[2];
    const float* Wh  = (const float*)d_in[3];
    const float* bh  = (const float*)d_in[4];
    float* out = (float*)d_out;
    char* ws = (char*)d_ws;

    if (ws_size < WS_NEEDED) {
        float* c_state = (float*)d_ws;
        for (int t = 0; t < T_; ++t)
            lstm_step<<<dim3(H_ / 4), dim3(256), 0, stream>>>(inp, Wx, bx, Wh, bh, out, c_state, t);
        return;
    }

    unsigned int*    flags = (unsigned int*)(ws + OFF_FLG);
    __hip_bfloat16*  Whb   = (__hip_bfloat16*)(ws + OFF_WHB);
    __hip_bfloat16*  Wxb   = (__hip_bfloat16*)(ws + OFF_WXB);
    __hip_bfloat16*  inp_b = (__hip_bfloat16*)(ws + OFF_INPB);  // becomes hseq after xg_gemm
    float*           bxh   = (float*)(ws + OFF_BXH);
    __hip_bfloat16*  xg    = (__hip_bfloat16*)(ws + OFF_XG);
    __hip_bfloat16*  hseq  = inp_b;

    hipMemsetAsync(flags, 0, 4096, stream);

    convert_all<<<dim3(4096), dim3(256), 0, stream>>>(inp, Wx, bx, Wh, bh, inp_b, Wxb, Whb, bxh);

    xg_gemm<<<dim3(BT / 128, G4 / 128), dim3(256), 0, stream>>>(inp_b, Wxb, bxh, xg);

    hipFuncSetAttribute((const void*)lstm_scan,
                        hipFuncAttributeMaxDynamicSharedMemorySize, SMEM_TOTAL);
    lstm_scan<<<dim3(NWG), dim3(512), SMEM_TOTAL, stream>>>(xg, Whb, out, hseq, flags);
}

// Round 14
// 2072.134 us; speedup vs baseline: 2.8964x; 1.0076x over previous
//
#include <hip/hip_runtime.h>
#include <hip/hip_bf16.h>
#include <math.h>

#define B_ 32
#define T_ 512
#define D_ 1024
#define H_ 1024
#define G4 4096
#define BT 16384
#define NWG 64

using bf16x8 = __attribute__((ext_vector_type(8))) short;
using f32x4  = __attribute__((ext_vector_type(4))) float;
typedef unsigned long long u64;
typedef unsigned int u32;

__device__ __forceinline__ float sigm(float x) { return 1.0f / (1.0f + __expf(-x)); }

// ---- workspace layout (bytes) ----
#define OFF_FLG   0ull                          // 64 flags, 64B stride = 4096
#define OFF_WHB   4096ull                       // Wh bf16 [4096][1024] = 8388608
#define OFF_WXB   (OFF_WHB + 8388608ull)        // Wx bf16 = 8388608
#define OFF_INPB  (OFF_WXB + 8388608ull)        // inp bf16 (reused as hseq[T][B][H]) = 33554432
#define OFF_BXH   (OFF_INPB + 33554432ull)      // bx+bh f32 [4096] = 16384
#define OFF_XG    (OFF_BXH + 16384ull)          // xg bf16 [T][NWG][4][32][16] = 134217728
#define WS_NEEDED (OFF_XG + 134217728ull)

// scan LDS: [0,65536) h-stage 32x2048B swizzled; [65536,74240) gbuf [32][4][17] f32;
// [74240,74244) lds_flag
#define SMEM_GBUF   65536
#define SMEM_LFLAG  74240
#define SMEM_TOTAL  74304

// ============ phase 1: convert inputs to bf16, fold biases (nt streaming reads) ============
__global__ __launch_bounds__(256) void convert_all(
    const float* __restrict__ inp, const float* __restrict__ Wx,
    const float* __restrict__ bx, const float* __restrict__ Wh,
    const float* __restrict__ bh,
    __hip_bfloat16* __restrict__ inp_b, __hip_bfloat16* __restrict__ Wx_b,
    __hip_bfloat16* __restrict__ Wh_b, float* __restrict__ bxh)
{
    const int gid = blockIdx.x * 256 + threadIdx.x;   // 0 .. 1048575
    {
        const f32x4* s = (const f32x4*)inp + (size_t)gid * 4;
        #pragma unroll
        for (int v = 0; v < 4; ++v) {
            f32x4 f = __builtin_nontemporal_load(s + v);
            size_t base = (size_t)gid * 16 + v * 4;
            inp_b[base + 0] = __float2bfloat16(f[0]);
            inp_b[base + 1] = __float2bfloat16(f[1]);
            inp_b[base + 2] = __float2bfloat16(f[2]);
            inp_b[base + 3] = __float2bfloat16(f[3]);
        }
    }
    {
        f32x4 fx = __builtin_nontemporal_load((const f32x4*)Wx + gid);
        f32x4 fh = __builtin_nontemporal_load((const f32x4*)Wh + gid);
        size_t base = (size_t)gid * 4;
        Wx_b[base + 0] = __float2bfloat16(fx[0]);
        Wx_b[base + 1] = __float2bfloat16(fx[1]);
        Wx_b[base + 2] = __float2bfloat16(fx[2]);
        Wx_b[base + 3] = __float2bfloat16(fx[3]);
        Wh_b[base + 0] = __float2bfloat16(fh[0]);
        Wh_b[base + 1] = __float2bfloat16(fh[1]);
        Wh_b[base + 2] = __float2bfloat16(fh[2]);
        Wh_b[base + 3] = __float2bfloat16(fh[3]);
    }
    if (gid < G4) bxh[gid] = bx[gid] + bh[gid];
}

// ============ phase 2: xg = X @ Wx^T + (bx+bh)  (128x128 LDS-staged, T2 swizzle) ============
// xg stores are NON-TEMPORAL: 128 MB written once, read once — keep it out of LLC
// so the scan's hot lines (flags, hseq) stay resident.
__global__ __launch_bounds__(256) void xg_gemm(
    const __hip_bfloat16* __restrict__ X,    // [BT][D], row = b*T + t
    const __hip_bfloat16* __restrict__ Wxb,  // [G4][D]
    const float* __restrict__ bxh,           // [G4]
    __hip_bfloat16* __restrict__ xg)         // [T][NWG][4][32][16]
{
    __shared__ __align__(16) char As[16384];
    __shared__ __align__(16) char Bs[16384];

    const int m0 = blockIdx.x * 128;
    const int n0 = blockIdx.y * 128;
    const int tid = threadIdx.x;
    const int lane = tid & 63;
    const int wv = tid >> 6;              // 0..3
    const int vr = wv >> 1, vc = wv & 1;  // 64x64 quadrant
    const int l15 = lane & 15;
    const int kg = (lane >> 4) * 8;

    const int srow_ = wv * 32 + (lane >> 3);
    const int scolb = (lane & 7) * 16;

    f32x4 acc[4][4] = {};

    for (int k0 = 0; k0 < D_; k0 += 64) {
        #pragma unroll
        for (int c = 0; c < 4; ++c) {
            const int row = srow_ + c * 8;
            const int cb  = scolb ^ ((row & 7) << 4);
            const char* ga = (const char*)X   + (size_t)(m0 + row) * 2048 + k0 * 2 + cb;
            const char* gb = (const char*)Wxb + (size_t)(n0 + row) * 2048 + k0 * 2 + cb;
            __builtin_amdgcn_global_load_lds(
                (const __attribute__((address_space(1))) void*)ga,
                (__attribute__((address_space(3))) void*)(As + wv * 4096 + c * 1024),
                16, 0, 0);
            __builtin_amdgcn_global_load_lds(
                (const __attribute__((address_space(1))) void*)gb,
                (__attribute__((address_space(3))) void*)(Bs + wv * 4096 + c * 1024),
                16, 0, 0);
        }
        __syncthreads();

        #pragma unroll
        for (int kk = 0; kk < 64; kk += 32) {
            bf16x8 af[4], bf[4];
            #pragma unroll
            for (int mi = 0; mi < 4; ++mi) {
                const int row = vr * 64 + mi * 16 + l15;
                af[mi] = *(const bf16x8*)(As + row * 128 + (((kk + kg) * 2) ^ ((row & 7) << 4)));
            }
            #pragma unroll
            for (int ni = 0; ni < 4; ++ni) {
                const int col = vc * 64 + ni * 16 + l15;
                bf[ni] = *(const bf16x8*)(Bs + col * 128 + (((kk + kg) * 2) ^ ((col & 7) << 4)));
            }
            #pragma unroll
            for (int mi = 0; mi < 4; ++mi)
                #pragma unroll
                for (int ni = 0; ni < 4; ++ni)
                    acc[mi][ni] = __builtin_amdgcn_mfma_f32_16x16x32_bf16(
                        af[mi], bf[ni], acc[mi][ni], 0, 0, 0);
        }
        __syncthreads();
    }

    #pragma unroll
    for (int ni = 0; ni < 4; ++ni) {
        const int col = n0 + vc * 64 + ni * 16 + l15;
        const int qq = col >> 10, ww = (col >> 4) & 63, jj = col & 15;
        const float bias = bxh[col];
        #pragma unroll
        for (int mi = 0; mi < 4; ++mi) {
            const int r0 = m0 + vr * 64 + mi * 16 + ((lane >> 4) << 2);
            #pragma unroll
            for (int r = 0; r < 4; ++r) {
                const int row = r0 + r;                 // = b*T + t
                const int bb = row >> 9, tt = row & 511;
                __hip_bfloat16 hb = __float2bfloat16(acc[mi][ni][r] + bias);
                unsigned short bits;
                __builtin_memcpy(&bits, &hb, 2);
                __builtin_nontemporal_store(bits,
                    (unsigned short*)&xg[(((size_t)tt * NWG + ww) * 4 + qq) * 512 + bb * 16 + jj]);
            }
        }
    }
}

// ============ phase 3: persistent recurrent scan (round-7 champion, + nt xg loads) ============
// 64 WGs x 512 threads. 3 barriers/step. wave0 polls 64 flags -> LDS-flag relay.
// h-stage via plain 16B loads; h published as shfl-packed u64 UC stores (all waves).
// xg loads NON-TEMPORAL: the 128MB read-once stream must not evict flags/hseq from LLC.
__global__ __launch_bounds__(512, 2) void lstm_scan(
    const __hip_bfloat16* __restrict__ xg,    // [T][NWG][4][32][16] (bias folded)
    const __hip_bfloat16* __restrict__ Whb,   // [G4][H]
    __hip_bfloat16* __restrict__ hseq,        // [T][B][H]
    unsigned int* __restrict__ flags)         // [NWG] at 64B stride
{
    extern __shared__ char smem[];
    float* gbuf = (float*)(smem + SMEM_GBUF);
    int* lds_flag = (int*)(smem + SMEM_LFLAG);

    const int w    = blockIdx.x;
    const int tid  = threadIdx.x;
    const int lane = tid & 63;
    const int wave = tid >> 6;
    const int mwave = wave >> 2;
    const int q     = wave & 3;
    const int l15   = lane & 15;
    const int kg    = (lane >> 4) * 8;

    if (tid == 0) *lds_flag = 0;

    // ---- pin this wave's Wh B-fragments (UC loads; land in AGPRs) ----
    bf16x8 bfrag[32];
    {
        const char* wrow = (const char*)(Whb + (size_t)(q * 1024 + w * 16 + l15) * H_);
        #pragma unroll
        for (int i = 0; i < 32; ++i) {
            u64 lo = __hip_atomic_load((const u64*)(wrow + (i * 32 + kg) * 2),
                                       __ATOMIC_RELAXED, __HIP_MEMORY_SCOPE_AGENT);
            u64 hi = __hip_atomic_load((const u64*)(wrow + (i * 32 + kg) * 2 + 8),
                                       __ATOMIC_RELAXED, __HIP_MEMORY_SCOPE_AGENT);
            union { u64 qv[2]; bf16x8 v; } u;
            u.qv[0] = lo; u.qv[1] = hi;
            bfrag[i] = u.v;
        }
    }

    const int pb  = tid >> 4;          // batch 0..31
    const int pjj = tid & 15;
    float cst = 0.0f;

    const int dbr   = mwave * 16 + ((lane >> 4) << 2);
    const int arow  = mwave * 16 + l15;
    const int abase = arow * 2048;
    const int axor  = (arow & 7) << 4;
    const int srow  = wave * 4 + (lane >> 4);           // staging row 0..31
    const int ql    = lane & 15;

    for (int t = 0; t < T_; ++t) {
        // xg prefetch (nt: read-once stream, don't pollute LLC); in flight during the wait
        float xgv[4];
        {
            const size_t sbase = (((size_t)t * NWG + w) * 4 + q) * 512;
            #pragma unroll
            for (int r = 0; r < 4; ++r) {
                unsigned short u = __builtin_nontemporal_load(
                    (const unsigned short*)&xg[sbase + (dbr + r) * 16 + l15]);
                __hip_bfloat16 bv;
                __builtin_memcpy(&bv, &u, 2);
                xgv[r] = __bfloat162float(bv);
            }
        }

        f32x4 acc = {};
        if (t > 0) {
            // ---- arrival: wave0 polls 64 flags, relays via LDS; others spin LDS ----
            if (wave == 0) {
                const unsigned int* fp = flags + lane * 16;
                while (__hip_atomic_load(fp, __ATOMIC_RELAXED, __HIP_MEMORY_SCOPE_AGENT)
                       < (unsigned)t)
                    __builtin_amdgcn_s_sleep(1);
                __hip_atomic_store(lds_flag, t, __ATOMIC_RELAXED,
                                   __HIP_MEMORY_SCOPE_WORKGROUP);
            } else {
                while (__hip_atomic_load(lds_flag, __ATOMIC_RELAXED,
                                         __HIP_MEMORY_SCOPE_WORKGROUP) < t)
                    __builtin_amdgcn_s_sleep(1);
            }
            asm volatile("" ::: "memory");

            // ---- stage h_{t-1} into LDS (plain 16B loads, XOR-swizzled writes) ----
            {
                const bf16x8* src = (const bf16x8*)(hseq + ((size_t)(t - 1) * B_ + srow) * H_);
                #pragma unroll
                for (int j = 0; j < 8; ++j) {
                    bf16x8 v = src[ql + j * 16];
                    *(bf16x8*)(smem + srow * 2048 + (((ql + j * 16) * 16) ^ ((srow & 7) << 4))) = v;
                }
            }
            __syncthreads();   // (A)

            // ---- 32 MFMAs, 4 accumulation chains ----
            f32x4 a0 = {}, a1 = {}, a2 = {}, a3 = {};
            #pragma unroll
            for (int i = 0; i < 8; ++i) {
                bf16x8 v0 = *(const bf16x8*)(smem + abase + ((((4 * i + 0) * 64) + kg * 2) ^ axor));
                bf16x8 v1 = *(const bf16x8*)(smem + abase + ((((4 * i + 1) * 64) + kg * 2) ^ axor));
                bf16x8 v2 = *(const bf16x8*)(smem + abase + ((((4 * i + 2) * 64) + kg * 2) ^ axor));
                bf16x8 v3 = *(const bf16x8*)(smem + abase + ((((4 * i + 3) * 64) + kg * 2) ^ axor));
                a0 = __builtin_amdgcn_mfma_f32_16x16x32_bf16(v0, bfrag[4 * i + 0], a0, 0, 0, 0);
                a1 = __builtin_amdgcn_mfma_f32_16x16x32_bf16(v1, bfrag[4 * i + 1], a1, 0, 0, 0);
                a2 = __builtin_amdgcn_mfma_f32_16x16x32_bf16(v2, bfrag[4 * i + 2], a2, 0, 0, 0);
                a3 = __builtin_amdgcn_mfma_f32_16x16x32_bf16(v3, bfrag[4 * i + 3], a3, 0, 0, 0);
            }
            acc = (a0 + a1) + (a2 + a3);
        }

        #pragma unroll
        for (int r = 0; r < 4; ++r)
            gbuf[((dbr + r) * 4 + q) * 17 + l15] = acc[r] + xgv[r];
        __syncthreads();   // (B)

        // ---- pointwise; pack h in-wave; parallel UC stores ----
        {
            float gi = sigm(gbuf[(pb * 4 + 0) * 17 + pjj]);
            float gf = sigm(gbuf[(pb * 4 + 1) * 17 + pjj]);
            float gg = sigm(gbuf[(pb * 4 + 2) * 17 + pjj]);  // sigmoid cell gate, per reference
            float go = sigm(gbuf[(pb * 4 + 3) * 17 + pjj]);
            cst = cst * gf + gi * gg;
            float h = go * tanhf(cst);
            __hip_bfloat16 hb = __float2bfloat16(h);
            unsigned short hs_;
            __builtin_memcpy(&hs_, &hb, 2);
            unsigned hu = hs_;
            unsigned h1 = __shfl_down(hu, 1, 64);
            unsigned h2 = __shfl_down(hu, 2, 64);
            unsigned h3 = __shfl_down(hu, 3, 64);
            if ((lane & 3) == 0) {
                u64 pv = (u64)hu | ((u64)h1 << 16) | ((u64)h2 << 32) | ((u64)h3 << 48);
                u64* dst = (u64*)(hseq + ((size_t)t * B_ + pb) * H_ + w * 16 + pjj);
                __hip_atomic_store(dst, pv, __ATOMIC_RELAXED, __HIP_MEMORY_SCOPE_AGENT);
            }
        }
        __syncthreads();   // (C) drains vmcnt -> all h stores acked at coherence point

        if (t < T_ - 1 && tid == 0)
            __hip_atomic_store(flags + w * 16, (unsigned)(t + 1),
                               __ATOMIC_RELAXED, __HIP_MEMORY_SCOPE_AGENT);
    }
}

// ============ phase 4: expand hseq bf16 [T][B][H] -> out f32 [B][T][H] (nt stores) ============
__global__ __launch_bounds__(256) void expand_out(
    const __hip_bfloat16* __restrict__ hseq, float* __restrict__ out)
{
    const size_t gid = (size_t)blockIdx.x * 256 + threadIdx.x;
    const size_t lin = gid * 8;
    const int t = (int)(lin >> 15);
    const int b = (int)((lin >> 10) & 31);
    const int h = (int)(lin & 1023);
    bf16x8 v = *(const bf16x8*)(hseq + lin);
    float* o = out + ((size_t)b * T_ + t) * H_ + h;
    #pragma unroll
    for (int i = 0; i < 8; ++i) {
        unsigned short s = (unsigned short)v[i];
        __hip_bfloat16 bv;
        __builtin_memcpy(&bv, &s, 2);
        __builtin_nontemporal_store(__bfloat162float(bv), o + i);
    }
}

// ============ fallback (round-1 slow path) if ws too small ============
__global__ __launch_bounds__(256) void lstm_step(
    const float* __restrict__ inp, const float* __restrict__ Wx,
    const float* __restrict__ bx, const float* __restrict__ Wh,
    const float* __restrict__ bh, float* __restrict__ out,
    float* __restrict__ c_state, int t)
{
    const int tid = threadIdx.x;
    const int lane = tid & 63;
    const int khalf = lane & 1;
    const int b = lane >> 1;
    const int j = blockIdx.x * 4 + (tid >> 6);
    const int k0 = khalf * (D_ / 2);
    float a0 = 0.f, a1 = 0.f, a2 = 0.f, a3 = 0.f;
    {
        const float* xrow = inp + ((size_t)b * T_ + t) * D_ + k0;
        const float* w0 = Wx + (size_t)(0 * H_ + j) * D_ + k0;
        const float* w1 = Wx + (size_t)(1 * H_ + j) * D_ + k0;
        const float* w2 = Wx + (size_t)(2 * H_ + j) * D_ + k0;
        const float* w3 = Wx + (size_t)(3 * H_ + j) * D_ + k0;
        for (int kk = 0; kk < D_ / 2; kk += 4) {
            float4 xv = *(const float4*)(xrow + kk);
            float4 v0 = *(const float4*)(w0 + kk), v1 = *(const float4*)(w1 + kk);
            float4 v2 = *(const float4*)(w2 + kk), v3 = *(const float4*)(w3 + kk);
            a0 = fmaf(xv.x, v0.x, fmaf(xv.y, v0.y, fmaf(xv.z, v0.z, fmaf(xv.w, v0.w, a0))));
            a1 = fmaf(xv.x, v1.x, fmaf(xv.y, v1.y, fmaf(xv.z, v1.z, fmaf(xv.w, v1.w, a1))));
            a2 = fmaf(xv.x, v2.x, fmaf(xv.y, v2.y, fmaf(xv.z, v2.z, fmaf(xv.w, v2.w, a2))));
            a3 = fmaf(xv.x, v3.x, fmaf(xv.y, v3.y, fmaf(xv.z, v3.z, fmaf(xv.w, v3.w, a3))));
        }
    }
    if (t > 0) {
        const float* hrow = out + ((size_t)b * T_ + (t - 1)) * H_ + k0;
        const float* w0 = Wh + (size_t)(0 * H_ + j) * H_ + k0;
        const float* w1 = Wh + (size_t)(1 * H_ + j) * H_ + k0;
        const float* w2 = Wh + (size_t)(2 * H_ + j) * H_ + k0;
        const float* w3 = Wh + (size_t)(3 * H_ + j) * H_ + k0;
        for (int kk = 0; kk < H_ / 2; kk += 4) {
            float4 hv = *(const float4*)(hrow + kk);
            float4 v0 = *(const float4*)(w0 + kk), v1 = *(const float4*)(w1 + kk);
            float4 v2 = *(const float4*)(w2 + kk), v3 = *(const float4*)(w3 + kk);
            a0 = fmaf(hv.x, v0.x, fmaf(hv.y, v0.y, fmaf(hv.z, v0.z, fmaf(hv.w, v0.w, a0))));
            a1 = fmaf(hv.x, v1.x, fmaf(hv.y, v1.y, fmaf(hv.z, v1.z, fmaf(hv.w, v1.w, a1))));
            a2 = fmaf(hv.x, v2.x, fmaf(hv.y, v2.y, fmaf(hv.z, v2.z, fmaf(hv.w, v2.w, a2))));
            a3 = fmaf(hv.x, v3.x, fmaf(hv.y, v3.y, fmaf(hv.z, v3.z, fmaf(hv.w, v3.w, a3))));
        }
    }
    a0 += __shfl_xor(a0, 1, 64); a1 += __shfl_xor(a1, 1, 64);
    a2 += __shfl_xor(a2, 1, 64); a3 += __shfl_xor(a3, 1, 64);
    if (khalf == 0) {
        float gi = sigm(a0 + bx[0 * H_ + j] + bh[0 * H_ + j]);
        float gf = sigm(a1 + bx[1 * H_ + j] + bh[1 * H_ + j]);
        float gg = sigm(a2 + bx[2 * H_ + j] + bh[2 * H_ + j]);
        float go = sigm(a3 + bx[3 * H_ + j] + bh[3 * H_ + j]);
        size_t ci = (size_t)b * H_ + j;
        float c = (t > 0) ? c_state[ci] : 0.0f;
        c = c * gf + gi * gg;
        c_state[ci] = c;
        out[((size_t)b * T_ + t) * H_ + j] = go * tanhf(c);
    }
}

extern "C" void kernel_launch(void* const* d_in, const int* in_sizes, int n_in,
                              void* d_out, int out_size, void* d_ws, size_t ws_size,
                              hipStream_t stream) {
    const float* inp = (const float*)d_in[0];
    const float* Wx  = (const float*)d_in[1];
    const float* bx  = (const float*)d_in[2];
    const float* Wh  = (const float*)d_in[3];
    const float* bh  = (const float*)d_in[4];
    float* out = (float*)d_out;
    char* ws = (char*)d_ws;

    if (ws_size < WS_NEEDED) {
        float* c_state = (float*)d_ws;
        for (int t = 0; t < T_; ++t)
            lstm_step<<<dim3(H_ / 4), dim3(256), 0, stream>>>(inp, Wx, bx, Wh, bh, out, c_state, t);
        return;
    }

    unsigned int*    flags = (unsigned int*)(ws + OFF_FLG);
    __hip_bfloat16*  Whb   = (__hip_bfloat16*)(ws + OFF_WHB);
    __hip_bfloat16*  Wxb   = (__hip_bfloat16*)(ws + OFF_WXB);
    __hip_bfloat16*  inp_b = (__hip_bfloat16*)(ws + OFF_INPB);  // becomes hseq after xg_gemm
    float*           bxh   = (float*)(ws + OFF_BXH);
    __hip_bfloat16*  xg    = (__hip_bfloat16*)(ws + OFF_XG);
    __hip_bfloat16*  hseq  = inp_b;

    (void)hipMemsetAsync(flags, 0, 4096, stream);

    convert_all<<<dim3(4096), dim3(256), 0, stream>>>(inp, Wx, bx, Wh, bh, inp_b, Wxb, Whb, bxh);

    xg_gemm<<<dim3(BT / 128, G4 / 128), dim3(256), 0, stream>>>(inp_b, Wxb, bxh, xg);

    static bool attr_set = false;
    if (!attr_set) {
        (void)hipFuncSetAttribute((const void*)lstm_scan,
                                  hipFuncAttributeMaxDynamicSharedMemorySize, SMEM_TOTAL);
        attr_set = true;
    }
    lstm_scan<<<dim3(NWG), dim3(512), SMEM_TOTAL, stream>>>(xg, Whb, hseq, flags);

    expand_out<<<dim3((BT * H_ / 8) / 256), dim3(256), 0, stream>>>(hseq, out);
}